// Round 3
// baseline (302.197 us; speedup 1.0000x reference)
//
#include <hip/hip_runtime.h>

// out[b,e,t] = v2[t]*x[b,e,t] + sum_{s<t} v[s]*x[b,e,s]*d^(t-s) + bias[t]
// => decayed prefix scan along last axis (first-order linear recurrence).
// One 64-lane WAVE per row (4 rows per 256-thread block): no __syncthreads,
// no LDS combine. Each lane owns 32 contiguous elements (8x float4).
// Scan operator: (s,p) o (s',p') = (s*p' + s', p*p'), per-lane aggregate
// (c, d^32). Pass 1 folds diag+bias+local-prefix into rp[]; pass 2 adds the
// wave-scanned carry C*d^k and stores.

#define SEQ 2048
#define THREADS 256
#define ROWS_PER_BLOCK 4
#define PER_LANE 32

__global__ __launch_bounds__(THREADS) void decay_scan_kernel(
    const float* __restrict__ x,
    const float* __restrict__ weight,
    const float* __restrict__ diag_weight,
    const float* __restrict__ bias,
    const float* __restrict__ decay,
    float* __restrict__ out)
{
    const int lane = threadIdx.x & 63;
    const int wv   = threadIdx.x >> 6;
    const long row  = (long)blockIdx.x * ROWS_PER_BLOCK + wv;
    const long base = row * SEQ;
    const int col0 = lane * PER_LANE;

    // d = clip(decay_value[1,0], 0.9, 1.0)
    float d = fminf(fmaxf(decay[1], 0.9f), 1.0f);
    const float d2 = d * d, d3 = d2 * d, d4 = d2 * d2;
    const float d8 = d4 * d4, d16 = d8 * d8, d32 = d16 * d16;

    // Pass 1: local decayed scan; rp[k] = lp[k] + x[k]*v2[k] + b[k]
    // where lp[k] = sum_{s<k in lane} x[s]*v[s]*d^(k-s).
    float rp[PER_LANE];
    float c = 0.f;
    #pragma unroll
    for (int j = 0; j < PER_LANE / 4; ++j) {
        const float4 xv = *(const float4*)(x + base + col0 + j * 4);
        const float4 vv = *(const float4*)(weight + col0 + j * 4);
        const float4 gv = *(const float4*)(diag_weight + col0 + j * 4);
        const float4 bv = *(const float4*)(bias + col0 + j * 4);
        const float xa[4] = {xv.x, xv.y, xv.z, xv.w};
        const float va[4] = {vv.x, vv.y, vv.z, vv.w};
        const float ga[4] = {gv.x, gv.y, gv.z, gv.w};
        const float ba[4] = {bv.x, bv.y, bv.z, bv.w};
        #pragma unroll
        for (int k = 0; k < 4; ++k) {
            rp[j * 4 + k] = fmaf(xa[k], ga[k], c + ba[k]);
            c = d * fmaf(xa[k], va[k], c);
        }
    }

    // Wave-level inclusive pair-scan on (c, d^32); no barriers needed.
    float s = c, p = d32;
    #pragma unroll
    for (int o = 1; o < 64; o <<= 1) {
        const float s2 = __shfl_up(s, o, 64);
        const float p2 = __shfl_up(p, o, 64);
        if (lane >= o) { s = fmaf(s2, p, s); p = p2 * p; }
    }
    // Exclusive carry at this lane's chunk start.
    float C = __shfl_up(s, 1, 64);
    if (lane == 0) C = 0.f;

    // Pass 2: out[k] = C*d^k + rp[k].  Short chain: t = C*d^(4j), t*d^{0..3}.
    float dkc = 1.f;
    #pragma unroll
    for (int j = 0; j < PER_LANE / 4; ++j) {
        const float t = C * dkc;
        float4 o4;
        o4.x = t + rp[j * 4 + 0];
        o4.y = fmaf(t, d,  rp[j * 4 + 1]);
        o4.z = fmaf(t, d2, rp[j * 4 + 2]);
        o4.w = fmaf(t, d3, rp[j * 4 + 3]);
        *(float4*)(out + base + col0 + j * 4) = o4;
        dkc *= d4;
    }
}

extern "C" void kernel_launch(void* const* d_in, const int* in_sizes, int n_in,
                              void* d_out, int out_size, void* d_ws, size_t ws_size,
                              hipStream_t stream) {
    const float* x           = (const float*)d_in[0];
    const float* weight      = (const float*)d_in[1];
    const float* diag_weight = (const float*)d_in[2];
    const float* bias        = (const float*)d_in[3];
    const float* decay       = (const float*)d_in[4];
    float* out = (float*)d_out;

    const int rows = in_sizes[0] / SEQ;  // B*E = 16384
    decay_scan_kernel<<<rows / ROWS_PER_BLOCK, THREADS, 0, stream>>>(
        x, weight, diag_weight, bias, decay, out);
}

// Round 4
// 237.776 us; speedup vs baseline: 1.2709x; 1.2709x over previous
//
#include <hip/hip_runtime.h>

// out[b,e,t] = v2[t]*x[b,e,t] + sum_{s<t} v[s]*x[b,e,s]*d^(t-s) + bias[t]
// => decayed prefix scan along the last axis (first-order linear recurrence).
//
// Structure (round-3): one 512-thread block per row, 4 contiguous elements
// per thread => every global float4 access is PERFECTLY coalesced (lanes
// 16 B apart). Round-2 post-mortem showed per-lane 128 B chunks make every
// VMEM instruction 8-way address-divergent (80->141 us regression); this
// reverts to the scan structure of round-1 but with ideal coalescing on both
// the x-load and the out-store (round-1 was 2-way divergent: 32 B stride).
//
// Scan operator on (sum, prod): (s,p) o (s',p') = (s*p' + s', p*p'),
// per-thread aggregate (c, d^4). Wave shfl-scan (6 steps) + one LDS combine
// across the 8 waves (single __syncthreads).

#define SEQ 2048
#define THREADS 512
#define PER_THREAD 4

__global__ __launch_bounds__(THREADS) void decay_scan_kernel(
    const float* __restrict__ x,
    const float* __restrict__ weight,
    const float* __restrict__ diag_weight,
    const float* __restrict__ bias,
    const float* __restrict__ decay,
    float* __restrict__ out)
{
    const int tid  = threadIdx.x;
    const int lane = tid & 63;
    const int wv   = tid >> 6;          // 8 waves
    const long base = (long)blockIdx.x * SEQ;
    const int off  = tid * PER_THREAD;  // 16 B stride => fully coalesced

    // d = clip(decay_value[1,0], 0.9, 1.0)
    float d = fminf(fmaxf(decay[1], 0.9f), 1.0f);
    const float d2 = d * d, d3 = d2 * d, d4 = d2 * d2;

    // Issue all loads up front (4 independent float4 in flight per thread).
    const float4 xv = *(const float4*)(x + base + off);
    const float4 vv = *(const float4*)(weight + off);
    const float4 gv = *(const float4*)(diag_weight + off);
    const float4 bv = *(const float4*)(bias + off);

    const float xa[4] = {xv.x, xv.y, xv.z, xv.w};
    const float va[4] = {vv.x, vv.y, vv.z, vv.w};

    // Local decayed scan over 4 elems; c ends as chunk aggregate
    // sum_k y[k] d^{4-k}, paired with p = d^4.
    float lp[PER_THREAD];
    float c = 0.f;
    #pragma unroll
    for (int k = 0; k < PER_THREAD; ++k) {
        lp[k] = c;
        c = d * fmaf(xa[k], va[k], c);
    }

    // Wave-level inclusive pair-scan on (c, d^4).
    float s = c, p = d4;
    #pragma unroll
    for (int o = 1; o < 64; o <<= 1) {
        const float s2 = __shfl_up(s, o, 64);
        const float p2 = __shfl_up(p, o, 64);
        if (lane >= o) { s = fmaf(s2, p, s); p = p2 * p; }
    }
    // Exclusive (within-wave) carry for this thread.
    float es = __shfl_up(s, 1, 64);
    float ep = __shfl_up(p, 1, 64);
    if (lane == 0) { es = 0.f; ep = 1.f; }

    // Cross-wave combine: 8 wave totals through LDS, one barrier.
    __shared__ float ws[8], wp[8];
    if (lane == 63) { ws[wv] = s; wp[wv] = p; }
    __syncthreads();
    float cs = 0.f;
    #pragma unroll
    for (int w = 0; w < 7; ++w) {
        if (w < wv) cs = fmaf(cs, wp[w], ws[w]);
    }
    // Full exclusive prefix P at this thread's chunk start.
    const float C = fmaf(cs, ep, es);

    // Epilogue: out[k] = C*d^k + lp[k] + x[k]*v2[k] + b[k]; coalesced store.
    float4 o4;
    o4.x = fmaf(xa[0], gv.x, C            + lp[0] + bv.x);
    o4.y = fmaf(xa[1], gv.y, fmaf(C, d,  lp[1]) + bv.y);
    o4.z = fmaf(xa[2], gv.z, fmaf(C, d2, lp[2]) + bv.z);
    o4.w = fmaf(xa[3], gv.w, fmaf(C, d3, lp[3]) + bv.w);
    *(float4*)(out + base + off) = o4;
}

extern "C" void kernel_launch(void* const* d_in, const int* in_sizes, int n_in,
                              void* d_out, int out_size, void* d_ws, size_t ws_size,
                              hipStream_t stream) {
    const float* x           = (const float*)d_in[0];
    const float* weight      = (const float*)d_in[1];
    const float* diag_weight = (const float*)d_in[2];
    const float* bias        = (const float*)d_in[3];
    const float* decay       = (const float*)d_in[4];
    float* out = (float*)d_out;

    const int rows = in_sizes[0] / SEQ;  // B*E = 16384
    decay_scan_kernel<<<rows, THREADS, 0, stream>>>(
        x, weight, diag_weight, bias, decay, out);
}